// Round 3
// baseline (910.175 us; speedup 1.0000x reference)
//
#include <hip/hip_runtime.h>

typedef unsigned short u16;
typedef __attribute__((ext_vector_type(8))) short short8;
typedef __attribute__((ext_vector_type(4))) float f32x4;

#define BB 4
#define SS 1024
#define HIDN 4096
#define HH 32
#define HKV 8
#define DD 128
#define RR 16
#define MM (BB * SS)
#define NQKV 6144   // 4096 q | 1024 k | 1024 v

__device__ __forceinline__ u16 f2bf(float f) {
    unsigned u = __builtin_bit_cast(unsigned, f);
    unsigned r = u + 0x7FFFu + ((u >> 16) & 1u);
    return (u16)(r >> 16);
}
__device__ __forceinline__ float bf2f(u16 u) {
    unsigned v = ((unsigned)u) << 16;
    return __builtin_bit_cast(float, v);
}
__device__ __forceinline__ void glds16(const u16* g, u16* l) {
    __builtin_amdgcn_global_load_lds((const __attribute__((address_space(1))) unsigned int*)g,
                                     (__attribute__((address_space(3))) unsigned int*)l, 16, 0, 0);
}

#define BAR()    asm volatile("s_barrier" ::: "memory")
#define VMCNT6() asm volatile("s_waitcnt vmcnt(6)" ::: "memory")

// ---------- 0. zero-fill ----------
__global__ void zero_kernel(float* __restrict__ p, int n) {
    int i = blockIdx.x * blockDim.x + threadIdx.x;
    if (i < n) p[i] = 0.f;
}

// ---------- 1. fp32 -> bf16 cast ----------
__global__ void cast_kernel(const float* __restrict__ src, u16* __restrict__ dst, int n4) {
    int i = blockIdx.x * blockDim.x + threadIdx.x;
    int stride = gridDim.x * blockDim.x;
    for (; i < n4; i += stride) {
        float4 v = reinterpret_cast<const float4*>(src)[i];
        ushort4 o;
        o.x = f2bf(v.x); o.y = f2bf(v.y); o.z = f2bf(v.z); o.w = f2bf(v.w);
        reinterpret_cast<ushort4*>(dst)[i] = o;
    }
}

// cast LoRA-A [B][16][HID] fp32 -> slice of Acat [B][48][HID] bf16
__global__ void cast_lora_a(const float* __restrict__ src, u16* __restrict__ dst,
                            int perB4, int dstStrideU16, int n4) {
    int i = blockIdx.x * blockDim.x + threadIdx.x;
    int stride = gridDim.x * blockDim.x;
    for (; i < n4; i += stride) {
        int b = i / perB4;
        int w4 = i - b * perB4;
        float4 v = reinterpret_cast<const float4*>(src)[i];
        ushort4 o;
        o.x = f2bf(v.x); o.y = f2bf(v.y); o.z = f2bf(v.z); o.w = f2bf(v.w);
        reinterpret_cast<ushort4*>(dst + (size_t)b * dstStrideU16)[w4] = o;
    }
}

// ---------- 2. LoRA down-proj via MFMA split-K ----------
template <int NT>
__global__ __launch_bounds__(256) void lora_mfma(
        const u16* __restrict__ Xb, const u16* __restrict__ Ab, float* __restrict__ T) {
    const int N = NT * 16;
    __shared__ __attribute__((aligned(16))) u16 Xls[128 * 32];
    __shared__ __attribute__((aligned(16))) u16 Als[NT * 16 * 32];
    int tid = threadIdx.x;
    int wave = tid >> 6, lane = tid & 63;
    int quad = lane >> 4, l15 = lane & 15;
    int m0 = blockIdx.y * 128;
    int b = m0 >> 10;
    int k0base = blockIdx.x * (HIDN / 4);
    const u16* Abb = Ab + (size_t)b * N * HIDN;
    f32x4 acc[2][NT] = {};
    int r0 = tid >> 2;
    int c0 = (tid & 3) * 8;
    for (int k0 = k0base; k0 < k0base + HIDN / 4; k0 += 32) {
        *(uint4*)&Xls[r0 * 32 + c0]        = *(const uint4*)&Xb[(size_t)(m0 + r0) * HIDN + k0 + c0];
        *(uint4*)&Xls[(r0 + 64) * 32 + c0] = *(const uint4*)&Xb[(size_t)(m0 + r0 + 64) * HIDN + k0 + c0];
        if (tid < NT * 16 * 4)
            *(uint4*)&Als[r0 * 32 + c0] = *(const uint4*)&Abb[(size_t)r0 * HIDN + k0 + c0];
        __syncthreads();
        short8 xf[2], af[NT];
#pragma unroll
        for (int mi = 0; mi < 2; mi++)
            xf[mi] = *(const short8*)&Xls[(wave * 32 + mi * 16 + l15) * 32 + quad * 8];
#pragma unroll
        for (int nt = 0; nt < NT; nt++)
            af[nt] = *(const short8*)&Als[(nt * 16 + l15) * 32 + quad * 8];
#pragma unroll
        for (int mi = 0; mi < 2; mi++)
#pragma unroll
            for (int nt = 0; nt < NT; nt++)
                acc[mi][nt] = __builtin_amdgcn_mfma_f32_16x16x32_bf16(xf[mi], af[nt], acc[mi][nt], 0, 0, 0);
        __syncthreads();
    }
#pragma unroll
    for (int mi = 0; mi < 2; mi++)
#pragma unroll
        for (int nt = 0; nt < NT; nt++)
#pragma unroll
            for (int r = 0; r < 4; r++) {
                int row = m0 + wave * 32 + mi * 16 + quad * 4 + r;
                atomicAdd(&T[(size_t)row * N + nt * 16 + l15], acc[mi][nt][r]);
            }
}

// ---------- 3. 256x256 8-phase GEMM: C = Xb*Wb^T + T*Bl^T (LoRA tail K-tile) ----------
// 8 waves (2M x 4N), BK=64, double-buffered LDS, counted vmcnt(6), XOR-swizzled LDS.
// QUADRANT phases: each phase computes one (M-half x N-half) C-quadrant for K=64
// so every MFMA only consumes fragments loaded THIS tile:
//   ph0: load afr(mi0-3)+bfr(ni0-1) -> MFMA mi0-3 x ni0-1
//   ph1: load bfr(ni2-3)            -> MFMA mi0-3 x ni2-3
//   ph2: load afr(mi4-7)            -> MFMA mi4-7 x ni0-1  (bfr held in regs)
//   ph3: no loads                   -> MFMA mi4-7 x ni2-3
// LDS region deaths: A-q0/q1 & B-h0 after ph0, B-h1 after ph1, A-q2/q3 after ph2.
// Stage schedule (2 glds/phase): ph0: Bh1@t+1 (other buf); ph1: A0,A1@t+2;
// ph2: Bh0j0,Bh0j1@t+2; ph3: A2,A3@t+2 + vmcnt(6) (drains exactly tile t+1's 8).
// lgkmcnt(0)+sched_barrier after the leading barrier pins the ds-read drain before
// the trailing barrier (rule #18) so the next window's stages can't overwrite mid-read.
#define GPH(DB, MB, NB, LOADA, LOADB, STG, ENDW) do {                                   \
    if (LOADA) {                                                                        \
        _Pragma("unroll") for (int q_ = 0; q_ < 4; q_++) {                              \
            int row_ = wm * 128 + ((MB) + q_) * 16 + l15; int sw_ = row_ & 7;           \
            _Pragma("unroll") for (int kk_ = 0; kk_ < 2; kk_++)                         \
                afr[q_][kk_] = *(const short8*)&As[DB][row_][((kk_ * 4 + quad) ^ sw_) * 8]; \
        }                                                                               \
    }                                                                                   \
    if (LOADB) {                                                                        \
        _Pragma("unroll") for (int j_ = 0; j_ < 2; j_++) {                              \
            int row_ = wn * 64 + ((NB) + j_) * 16 + l15; int sw_ = row_ & 7;            \
            _Pragma("unroll") for (int kk_ = 0; kk_ < 2; kk_++)                         \
                bfr[(NB) + j_][kk_] = *(const short8*)&Bs[DB][row_][((kk_ * 4 + quad) ^ sw_) * 8]; \
        }                                                                               \
    }                                                                                   \
    STG;                                                                                \
    BAR();                                                                              \
    asm volatile("s_waitcnt lgkmcnt(0)" ::: "memory");                                  \
    __builtin_amdgcn_sched_barrier(0);                                                  \
    __builtin_amdgcn_s_setprio(1);                                                      \
    _Pragma("unroll") for (int kk_ = 0; kk_ < 2; kk_++)                                 \
    _Pragma("unroll") for (int q_ = 0; q_ < 4; q_++)                                    \
    _Pragma("unroll") for (int j_ = 0; j_ < 2; j_++)                                    \
        acc[(MB) + q_][(NB) + j_] = __builtin_amdgcn_mfma_f32_16x16x32_bf16(            \
            afr[q_][kk_], bfr[(NB) + j_][kk_], acc[(MB) + q_][(NB) + j_], 0, 0, 0);     \
    __builtin_amdgcn_s_setprio(0);                                                      \
    ENDW;                                                                               \
    BAR();                                                                              \
} while (0)

__global__ __launch_bounds__(512, 2) void gemm256(
        const u16* __restrict__ Xb, const u16* __restrict__ Wb,
        const float* __restrict__ T, int tstride,
        const float* __restrict__ Bl0, const float* __restrict__ Bl1, const float* __restrict__ Bl2,
        int ns0, int ns1, int ns2, int secb0, int secb1,
        void* __restrict__ outp, int Nout, int out_f32) {
    const int K = HIDN;
    const int NKT = K / 64;          // 64 K-tiles
    __shared__ __attribute__((aligned(16))) u16 As[2][256][64];
    __shared__ __attribute__((aligned(16))) u16 Bs[2][256][64];
    int tid = threadIdx.x;
    int wave = tid >> 6, lane = tid & 63;
    int quad = lane >> 4, l15 = lane & 15;
    int wm = wave >> 2, wn = wave & 3;
    int m0 = blockIdx.y * 256, n0 = blockIdx.x * 256;
    int b = m0 >> 10;

    // section select (256-col blocks never cross q|k|v boundaries)
    int sec = (n0 >= secb0) + (n0 >= secb1);
    const float* Blp = (sec == 0) ? Bl0 : ((sec == 1) ? Bl1 : Bl2);
    int nsec = (sec == 0) ? ns0 : ((sec == 1) ? ns1 : ns2);
    int colbase = (sec == 0) ? 0 : ((sec == 1) ? secb0 : secb1);
    int toff = sec * 16;
    const float* BlB = Blp + (size_t)b * nsec * RR;

    // ---- staging precompute: pre-swizzled global source (32-bit offsets), linear LDS dest ----
    int rlo = lane >> 3;             // row within an 8-row issue
    int cch = lane & 7;              // linear 16B chunk within 128B row
    unsigned offA[4]; int lA[4];
#pragma unroll
    for (int q = 0; q < 4; q++) {
        int rb = ((wave & 4) << 5) + q * 32 + (wave & 3) * 8;   // A quarter q rows
        int r = rb + rlo;
        int g = cch ^ (r & 7);
        offA[q] = (unsigned)((m0 + r) * K + g * 8);
        lA[q] = rb;
    }
    unsigned offB[2][2]; int lB[2][2];
#pragma unroll
    for (int h = 0; h < 2; h++)
#pragma unroll
        for (int j = 0; j < 2; j++) {
            int u = wave * 2 + j;
            int rb = (u >> 2) * 64 + (u & 3) * 8 + h * 32;       // B half h rows
            int r = rb + rlo;
            int g = cch ^ (r & 7);
            offB[h][j] = (unsigned)((n0 + r) * K + g * 8);
            lB[h][j] = rb;
        }

    auto stA = [&](int db, int q, int kofs) { glds16(Xb + offA[q] + kofs, &As[db][lA[q]][0]); };
    auto stB = [&](int db, int h, int j, int kofs) { glds16(Wb + offB[h][j] + kofs, &Bs[db][lB[h][j]][0]); };

    f32x4 acc[8][4] = {};
    short8 afr[4][2];
    short8 bfr[4][2];

    // ---- prologue: tile0 -> buf0 (8 issues), tile1 -> buf1 minus Bh1 (6 issues) ----
    stA(0, 0, 0); stA(0, 1, 0); stB(0, 0, 0, 0); stB(0, 0, 1, 0);
    stA(0, 2, 0); stA(0, 3, 0); stB(0, 1, 0, 0); stB(0, 1, 1, 0);
    stA(1, 0, 64); stA(1, 1, 64); stB(1, 0, 0, 64); stB(1, 0, 1, 64);
    stA(1, 2, 64); stA(1, 3, 64);
    VMCNT6();   // oldest 8 (tile0) landed
    BAR();

    // ---- main loop: 32 iterations x 2 K-tiles ----
    for (int it = 0; it < NKT / 2; ++it) {
        int t2 = 2 * it + 2, t3 = 2 * it + 3;
        int k1 = (2 * it + 1) * 64;                // tile 2it+1 (always < NKT)
        int k2 = (t2 < NKT ? t2 : NKT - 1) * 64;   // clamped: rewrites identical bytes
        int k3 = (t3 < NKT ? t3 : NKT - 1) * 64;

        // tile 2it on buf0
        GPH(0, 0, 0, 1, 1, { stB(1, 1, 0, k1); stB(1, 1, 1, k1); }, );
        GPH(0, 0, 2, 0, 1, { stA(0, 0, k2); stA(0, 1, k2); }, );
        GPH(0, 4, 0, 1, 0, { stB(0, 0, 0, k2); stB(0, 0, 1, k2); }, );
        GPH(0, 4, 2, 0, 0, { stA(0, 2, k2); stA(0, 3, k2); }, VMCNT6());
        // tile 2it+1 on buf1
        GPH(1, 0, 0, 1, 1, { stB(0, 1, 0, k2); stB(0, 1, 1, k2); }, );
        GPH(1, 0, 2, 0, 1, { stA(1, 0, k3); stA(1, 1, k3); }, );
        GPH(1, 4, 0, 1, 0, { stB(1, 0, 0, k3); stB(1, 0, 1, k3); }, );
        GPH(1, 4, 2, 0, 0, { stA(1, 2, k3); stA(1, 3, k3); }, VMCNT6());
    }

    // ---- LoRA tail: drain, fill buf0 with T (A) and Bl (B), one K-slice of MFMA ----
    __syncthreads();    // drains vmcnt (in-flight clamped stages) + lgkm
    {
        int r = tid & 255;
        int sw = r & 7;
        short8 z = {0, 0, 0, 0, 0, 0, 0, 0};
        u16* dst; const float* srcp;
        if (tid < 256) { dst = &As[0][r][0]; srcp = T + (size_t)(m0 + r) * tstride + toff; }
        else           { dst = &Bs[0][r][0]; srcp = BlB + (size_t)(n0 - colbase + r) * RR; }
        short8 c0v, c1v;
#pragma unroll
        for (int e = 0; e < 8; e++) { c0v[e] = (short)f2bf(srcp[e]); c1v[e] = (short)f2bf(srcp[8 + e]); }
        *(short8*)&dst[(0 ^ sw) * 8] = c0v;
        *(short8*)&dst[(1 ^ sw) * 8] = c1v;
#pragma unroll
        for (int g = 2; g < 8; g++) *(short8*)&dst[(g ^ sw) * 8] = z;
    }
    __syncthreads();
    {
        short8 bt[4];
#pragma unroll
        for (int ni = 0; ni < 4; ni++) {
            int row = wn * 64 + ni * 16 + l15; int sw = row & 7;
            bt[ni] = *(const short8*)&Bs[0][row][(quad ^ sw) * 8];
        }
#pragma unroll
        for (int mi = 0; mi < 8; mi++) {
            int row = wm * 128 + mi * 16 + l15; int sw = row & 7;
            short8 at = *(const short8*)&As[0][row][(quad ^ sw) * 8];
#pragma unroll
            for (int ni = 0; ni < 4; ni++)
                acc[mi][ni] = __builtin_amdgcn_mfma_f32_16x16x32_bf16(at, bt[ni], acc[mi][ni], 0, 0, 0);
        }
    }

    // ---- epilogue store ----
#pragma unroll
    for (int mi = 0; mi < 8; mi++) {
#pragma unroll
        for (int r = 0; r < 4; r++) {
            int row = m0 + wm * 128 + mi * 16 + quad * 4 + r;
            if (out_f32) {
                float* op = (float*)outp;
#pragma unroll
                for (int ni = 0; ni < 4; ni++)
                    op[(size_t)row * Nout + n0 + wn * 64 + ni * 16 + l15] = acc[mi][ni][r];
            } else {
                u16* op = (u16*)outp;
#pragma unroll
                for (int ni = 0; ni < 4; ni++)
                    op[(size_t)row * Nout + n0 + wn * 64 + ni * 16 + l15] = f2bf(acc[mi][ni][r]);
            }
        }
    }
}

// ---------- 4. RoPE in place (strided rows) ----------
__global__ void rope_kernel(u16* __restrict__ x, int lognh, int rowstride, int total) {
    int idx = blockIdx.x * 256 + threadIdx.x;
    if (idx >= total) return;
    int d = idx & 63;
    int t = idx >> 6;                      // row*nh + h
    int h = t & ((1 << lognh) - 1);
    int row = t >> lognh;
    int pos = row & (SS - 1);
    size_t base = (size_t)row * rowstride + h * DD;
    float inv = __expf(-(float)d * (9.210340371976184f / 64.0f));
    float ang = (float)pos * inv;
    float c = cosf(ang), s = sinf(ang);
    float x1 = bf2f(x[base + d]);
    float x2 = bf2f(x[base + 64 + d]);
    x[base + d]      = f2bf(x1 * c - x2 * s);
    x[base + 64 + d] = f2bf(x2 * c + x1 * s);
}

// ---------- 5. flash attention: BQ=128, BK=64, V transposed; strided Q/K/V rows ----------
#define KLD 136
#define VTLD 72
#define PLD 72
__global__ __launch_bounds__(256) void flash_kernel(
        const u16* __restrict__ Q, const u16* __restrict__ Kx, const u16* __restrict__ V,
        u16* __restrict__ Oa, int qs, int kvs) {
    __shared__ __attribute__((aligned(16))) u16 Kls[64 * KLD];
    __shared__ __attribute__((aligned(16))) u16 Vt[128 * VTLD];
    __shared__ __attribute__((aligned(16))) u16 Pls[4 * 32 * PLD];
    int tid = threadIdx.x;
    int wave = tid >> 6, lane = tid & 63;
    int quad = lane >> 4, l15 = lane & 15;
    int blk = blockIdx.x;
    int qt = 7 - (blk >> 7);
    int h  = blk & 31;
    int b  = (blk >> 5) & 3;
    int hkv = h >> 2;
    int q0 = qt * 128;
    const float scale = 0.08838834764831845f;

    short8 qf[2][4];
#pragma unroll
    for (int mi = 0; mi < 2; mi++) {
        int qrow = q0 + (wave + 4 * mi) * 16 + l15;
        const u16* qp = Q + (size_t)(b * SS + qrow) * qs + h * DD;
#pragma unroll
        for (int kt = 0; kt < 4; kt++) qf[mi][kt] = *(const short8*)&qp[kt * 32 + quad * 8];
    }

    f32x4 oacc[2][8] = {};
    float mrow[2][4], lrow[2][4];
#pragma unroll
    for (int mi = 0; mi < 2; mi++)
#pragma unroll
        for (int r = 0; r < 4; r++) { mrow[mi][r] = -3.0e38f; lrow[mi][r] = 0.f; }

    int krow = tid >> 2;
    int kc   = (tid & 3) * 32;
    int vp   = tid >> 3;
    int vc   = (tid & 7) * 16;

    int nkb = (q0 >> 6) + 2;
    for (int ib = 0; ib < nkb; ib++) {
        int kb = ib * 64;
        const u16* kg = Kx + (size_t)(b * SS + kb + krow) * kvs + hkv * DD + kc;
#pragma unroll
        for (int j = 0; j < 4; j++)
            *(uint4*)&Kls[krow * KLD + kc + j * 8] = *(const uint4*)&kg[j * 8];
        const u16* vg0 = V + (size_t)(b * SS + kb + 2 * vp) * kvs + hkv * DD + vc;
        const u16* vg1 = vg0 + kvs;
#pragma unroll
        for (int j = 0; j < 2; j++) {
            uint4 a4 = *(const uint4*)&vg0[j * 8];
            uint4 b4 = *(const uint4*)&vg1[j * 8];
            const u16* ap = (const u16*)&a4;
            const u16* bp = (const u16*)&b4;
#pragma unroll
            for (int e = 0; e < 8; e++) {
                unsigned pk = (unsigned)ap[e] | ((unsigned)bp[e] << 16);
                *(unsigned*)&Vt[(size_t)(vc + j * 8 + e) * VTLD + 2 * vp] = pk;
            }
        }
        __syncthreads();

        f32x4 sa[2][4] = {};
#pragma unroll
        for (int nt = 0; nt < 4; nt++) {
            short8 kf[4];
#pragma unroll
            for (int kt = 0; kt < 4; kt++)
                kf[kt] = *(const short8*)&Kls[(nt * 16 + l15) * KLD + kt * 32 + quad * 8];
#pragma unroll
            for (int mi = 0; mi < 2; mi++)
#pragma unroll
                for (int kt = 0; kt < 4; kt++)
                    sa[mi][nt] = __builtin_amdgcn_mfma_f32_16x16x32_bf16(qf[mi][kt], kf[kt], sa[mi][nt], 0, 0, 0);
        }

#pragma unroll
        for (int mi = 0; mi < 2; mi++) {
#pragma unroll
            for (int r = 0; r < 4; r++) {
                int qpos = q0 + (wave + 4 * mi) * 16 + quad * 4 + r;
                float s[4];
#pragma unroll
                for (int nt = 0; nt < 4; nt++) {
                    float v = sa[mi][nt][r] * scale;
                    int kpos = kb + nt * 16 + l15;
                    s[nt] = (kpos > qpos) ? -3.0e38f : v;
                }
                float mx = fmaxf(fmaxf(s[0], s[1]), fmaxf(s[2], s[3]));
#pragma unroll
                for (int off = 1; off < 16; off <<= 1) mx = fmaxf(mx, __shfl_xor(mx, off, 64));
                float mnew = fmaxf(mrow[mi][r], mx);
                float alpha = __expf(mrow[mi][r] - mnew);
                mrow[mi][r] = mnew;
                float sum = 0.f;
#pragma unroll
                for (int nt = 0; nt < 4; nt++) {
                    float e = __expf(s[nt] - mnew);
                    sum += e;
                    Pls[wave * (32 * PLD) + (mi * 16 + quad * 4 + r) * PLD + nt * 16 + l15] = f2bf(e);
                }
#pragma unroll
                for (int off = 1; off < 16; off <<= 1) sum += __shfl_xor(sum, off, 64);
                lrow[mi][r] = lrow[mi][r] * alpha + sum;
#pragma unroll
                for (int dt = 0; dt < 8; dt++) oacc[mi][dt][r] *= alpha;
            }
        }
        __syncthreads();

#pragma unroll
        for (int kt = 0; kt < 2; kt++) {
            short8 pf[2];
#pragma unroll
            for (int mi = 0; mi < 2; mi++)
                pf[mi] = *(const short8*)&Pls[wave * (32 * PLD) + (mi * 16 + l15) * PLD + kt * 32 + quad * 8];
#pragma unroll
            for (int dt = 0; dt < 8; dt++) {
                short8 vf = *(const short8*)&Vt[(size_t)(dt * 16 + l15) * VTLD + kt * 32 + quad * 8];
#pragma unroll
                for (int mi = 0; mi < 2; mi++)
                    oacc[mi][dt] = __builtin_amdgcn_mfma_f32_16x16x32_bf16(pf[mi], vf, oacc[mi][dt], 0, 0, 0);
            }
        }
        __syncthreads();
    }

#pragma unroll
    for (int mi = 0; mi < 2; mi++)
#pragma unroll
        for (int r = 0; r < 4; r++) {
            float inv = 1.0f / lrow[mi][r];
            int orow = q0 + (wave + 4 * mi) * 16 + quad * 4 + r;
            u16* op = Oa + ((size_t)(b * SS + orow) * HH + h) * DD;
#pragma unroll
            for (int dt = 0; dt < 8; dt++)
                op[dt * 16 + l15] = f2bf(oacc[mi][dt][r] * inv);
        }
}

// ---------- launch ----------
extern "C" void kernel_launch(void* const* d_in, const int* in_sizes, int n_in,
                              void* d_out, int out_size, void* d_ws, size_t ws_size,
                              hipStream_t stream) {
    const float* X  = (const float*)d_in[0];
    const float* Wq = (const float*)d_in[1];
    const float* Wk = (const float*)d_in[2];
    const float* Wv = (const float*)d_in[3];
    const float* Wo = (const float*)d_in[4];
    const float* Aq = (const float*)d_in[5];
    const float* Bq = (const float*)d_in[6];
    const float* Ak = (const float*)d_in[7];
    const float* Bk = (const float*)d_in[8];
    const float* Av = (const float*)d_in[9];
    const float* Bv = (const float*)d_in[10];
    const float* Ao = (const float*)d_in[11];
    const float* Bo = (const float*)d_in[12];

    char* w = (char*)d_ws;
    auto take = [&](size_t bytes) {
        char* p = w;
        w += (bytes + 255) & ~(size_t)255;
        return p;
    };
    u16*   Xb  = (u16*)  take((size_t)MM * HIDN * 2);
    u16*   Wqb = (u16*)  take((size_t)HIDN * HIDN * 2);     // Wq|Wk|Wv contiguous (sizes are 256B multiples)
    u16*   Wkb = (u16*)  take((size_t)1024 * HIDN * 2);
    u16*   Wvb = (u16*)  take((size_t)1024 * HIDN * 2);
    u16*   Wob = (u16*)  take((size_t)HIDN * HIDN * 2);
    float* Tcat= (float*)take((size_t)MM * 48 * 4);          // q|k|v lora-down, [M][48]
    float* To  = (float*)take((size_t)MM * 16 * 4);          // o lora-down, [M][16]
    u16*   Acat= (u16*)  take((size_t)BB * 48 * HIDN * 2);
    u16*   Aob = (u16*)  take((size_t)BB * 16 * HIDN * 2);
    u16*   qkv = (u16*)  take((size_t)MM * NQKV * 2);        // [M][6144] = q|k|v packed
    u16*   attn = Xb;   // Xb dead after QKV GEMM

    (void)Wkb; (void)Wvb;

    zero_kernel<<<(MM * 64 + 255) / 256, 256, 0, stream>>>(Tcat, MM * 64);

    cast_kernel<<<2048, 256, 0, stream>>>(X,  Xb,  MM * HIDN / 4);
    cast_kernel<<<2048, 256, 0, stream>>>(Wq, Wqb, HIDN * HIDN / 4);
    cast_kernel<<<1024, 256, 0, stream>>>(Wk, Wkb, 1024 * HIDN / 4);
    cast_kernel<<<1024, 256, 0, stream>>>(Wv, Wvb, 1024 * HIDN / 4);
    cast_kernel<<<2048, 256, 0, stream>>>(Wo, Wob, HIDN * HIDN / 4);
    {
        const int perB4 = 16 * HIDN / 4;
        const int n4 = BB * perB4;
        cast_lora_a<<<256, 256, 0, stream>>>(Aq, Acat,             perB4, 48 * HIDN, n4);
        cast_lora_a<<<256, 256, 0, stream>>>(Ak, Acat + 16 * HIDN, perB4, 48 * HIDN, n4);
        cast_lora_a<<<256, 256, 0, stream>>>(Av, Acat + 32 * HIDN, perB4, 48 * HIDN, n4);
        cast_kernel<<<256, 256, 0, stream>>>(Ao, Aob, BB * 16 * HIDN / 4);
    }

    lora_mfma<3><<<dim3(4, 32), 256, 0, stream>>>(Xb, Acat, Tcat);

    // fused Q|K|V projection GEMM, N=6144, 256^2 8-phase, LoRA folded into tail K-tile
    gemm256<<<dim3(24, 16), 512, 0, stream>>>(
        Xb, Wqb, Tcat, 48, Bq, Bk, Bv, HIDN, 1024, 1024, 4096, 5120,
        (void*)qkv, NQKV, 0);

    rope_kernel<<<(BB * SS * HH * 64 + 255) / 256, 256, 0, stream>>>(qkv,        5, NQKV, BB * SS * HH * 64);
    rope_kernel<<<(BB * SS * HKV * 64 + 255) / 256, 256, 0, stream>>>(qkv + 4096, 3, NQKV, BB * SS * HKV * 64);

    flash_kernel<<<BB * HH * (SS / 128), 256, 0, stream>>>(qkv, qkv + 4096, qkv + 5120, attn, NQKV, NQKV);

    lora_mfma<1><<<dim3(4, 32), 256, 0, stream>>>(attn, Aob, To);

    // O projection GEMM (single section), fp32 out
    gemm256<<<dim3(16, 16), 512, 0, stream>>>(
        attn, Wob, To, 16, Bo, Bo, Bo, HIDN, HIDN, HIDN, 1 << 30, 1 << 30,
        (void*)d_out, HIDN, 1);
}